// Round 12
// baseline (155.286 us; speedup 1.0000x reference)
//
#include <hip/hip_runtime.h>

// B=2, D=64, N=512, H=256, OUT=64
// mid[b] = sum_{c,i} relu( relu(hi[b,i,:]+hcb[b,c,:]) @ w2 + b2 ) @ w3 + N^2*b3
// out = relu(mid @ w4 + b4) @ w5 + b5
//
// big v12: BARRIER-FREE main loop. Whole B (fragment-ordered w2^T) lives in
// 128 KB LDS, staged once per block. Each of 8 waves free-runs 4 jobs:
// job = 64 pair-rows (two 32-row MFMA tiles) x 256 cols. A generated into 128
// persistent fragment regs; per col-block n: 16 x {ds_read_b128 + 2 MFMA}.
// One B-read feeds 2 MFMAs. acc pair only (n-loop unroll 1). Waves anti-phase
// naturally (no __syncthreads after stage) -> gen hides under co-wave MFMA.

using f32x16  = __attribute__((ext_vector_type(16))) float;
using short8  = __attribute__((ext_vector_type(8))) short;
using float4v = __attribute__((ext_vector_type(4))) float;

__device__ __forceinline__ short f2bf(float f) {
    unsigned u = __float_as_uint(f);
    unsigned r = u + 0x7FFFu + ((u >> 16) & 1u);   // RNE
    return (short)(r >> 16);
}

__device__ __forceinline__ short8 relu_pack8(float4v lo, float4v hi4) {
#pragma unroll
    for (int e = 0; e < 4; ++e) {
        lo[e]  = fmaxf(lo[e], 0.f);
        hi4[e] = fmaxf(hi4[e], 0.f);
    }
    union { short8 s; unsigned u[4]; } r;
    asm("v_cvt_pk_bf16_f32 %0, %1, %2" : "=v"(r.u[0]) : "v"(lo[0]),  "v"(lo[1]));
    asm("v_cvt_pk_bf16_f32 %0, %1, %2" : "=v"(r.u[1]) : "v"(lo[2]),  "v"(lo[3]));
    asm("v_cvt_pk_bf16_f32 %0, %1, %2" : "=v"(r.u[2]) : "v"(hi4[0]), "v"(hi4[1]));
    asm("v_cvt_pk_bf16_f32 %0, %1, %2" : "=v"(r.u[3]) : "v"(hi4[2]), "v"(hi4[3]));
    return r.s;
}

// ---- prep: blocks [0,256): hi/hcb (4 n-cols per block, w1 traffic /4);
//            blocks [256,512): fragment-ordered w2 (verified layout from R7)
__global__ __launch_bounds__(256) void prep(const float* __restrict__ in,
                                            const float* __restrict__ w1,
                                            const float* __restrict__ b1,
                                            const float* __restrict__ w2,
                                            float* __restrict__ hi,
                                            float* __restrict__ hcb,
                                            short* __restrict__ bfrag) {
    int tid = threadIdx.x;
    int bidx = blockIdx.x;
    if (bidx < 256) {
        int b = bidx >> 7, n0 = (bidx & 127) * 4;
        __shared__ float xs[4][64];
        {
            int nn = tid >> 6, d = tid & 63;
            xs[nn][d] = in[(size_t)(b * 64 + d) * 512 + n0 + nn];
        }
        __syncthreads();
        float a0[4] = {0.f, 0.f, 0.f, 0.f}, a1[4] = {0.f, 0.f, 0.f, 0.f};
#pragma unroll 8
        for (int d = 0; d < 64; ++d) {
            float wA = w1[d * 256 + tid];
            float wB = w1[(64 + d) * 256 + tid];
#pragma unroll
            for (int nn = 0; nn < 4; ++nn) {
                a0[nn] += xs[nn][d] * wA;
                a1[nn] += xs[nn][d] * wB;
            }
        }
        float bb = b1[tid];
#pragma unroll
        for (int nn = 0; nn < 4; ++nn) {
            size_t o = (size_t)(b * 512 + n0 + nn) * 256 + tid;
            hi[o]  = a0[nn];
            hcb[o] = a1[nn] + bb;
        }
    } else {
        // off = ((n*16+kk)*64 + h*32+col)*8 + j ; value bf16(w2[k][ncol])
        // k = 16kk+8h+j, ncol = n*32+col  (n = 0..7)
        int idx = (bidx - 256) * 256 + tid;        // [0, 65536)
        int k = idx >> 8, ncol = idx & 255;
        int n = ncol >> 5, col = ncol & 31;
        int kk = k >> 4, h = (k >> 3) & 1, j = k & 7;
        int off = (((n * 16 + kk) * 64) + h * 32 + col) * 8 + j;
        bfrag[off] = f2bf(w2[k * 256 + ncol]);
    }
}

// ---- big v12: 256 blocks x 512 threads (8 waves), 128 KB LDS (whole B)
__global__ __launch_bounds__(512, 2) void big(const float* __restrict__ hi_,
                                              const float* __restrict__ hcb_,
                                              const short8* __restrict__ bfrag,
                                              const float* __restrict__ b2,
                                              float* __restrict__ partials) {
    __shared__ __align__(16) short8 Blds[8192];   // [n 8][kk 16][lane 64] = 128 KB

    const int tid = threadIdx.x;                  // 0..511
    const int bid = blockIdx.x;                   // [0,256)
    const int b = bid >> 7, r = bid & 127;

    // stage whole B once (linear, coalesced)
#pragma unroll
    for (int q = 0; q < 16; ++q) Blds[q * 512 + tid] = bfrag[q * 512 + tid];
    __syncthreads();                              // the ONLY block-wide barrier

    const int w = tid >> 6, lane = tid & 63;
    const int l31 = lane & 31, h = lane >> 5;
    const int ip = l31 & 7, cq4 = l31 >> 3;

    const int C = r >> 1;                         // c-octet [0,64)
    const int Ibase = (r & 1) * 32 + w * 4;       // i-octet base

    const float* __restrict__ hib = hi_  + (size_t)b * 131072;
    const float* __restrict__ hc0 = hcb_ + (size_t)b * 131072
                                  + (size_t)(C * 8 + cq4) * 256 + h * 8;
    const float* __restrict__ hc1 = hc0 + 4 * 256;

    float b2v[8];
#pragma unroll
    for (int n = 0; n < 8; ++n) b2v[n] = b2[n * 32 + l31];
    float jobsum[8] = {0.f, 0.f, 0.f, 0.f, 0.f, 0.f, 0.f, 0.f};

#pragma unroll 1
    for (int t = 0; t < 4; ++t) {
        const int I = Ibase + t;
        const float* __restrict__ hirow = hib + (size_t)(I * 8 + ip) * 256 + h * 8;

        // ---- gen: two 32-row A tiles into 128 fragment regs
        short8 A0[16], A1[16];
#pragma unroll
        for (int kk = 0; kk < 16; ++kk) {
            float4v x0  = *reinterpret_cast<const float4v*>(hirow + kk * 16);
            float4v x1  = *reinterpret_cast<const float4v*>(hirow + kk * 16 + 4);
            float4v c00 = *reinterpret_cast<const float4v*>(hc0 + kk * 16);
            float4v c01 = *reinterpret_cast<const float4v*>(hc0 + kk * 16 + 4);
            float4v c10 = *reinterpret_cast<const float4v*>(hc1 + kk * 16);
            float4v c11 = *reinterpret_cast<const float4v*>(hc1 + kk * 16 + 4);
            A0[kk] = relu_pack8(x0 + c00, x1 + c01);
            A1[kk] = relu_pack8(x0 + c10, x1 + c11);
            if (kk & 1) __builtin_amdgcn_sched_barrier(0);   // cap load hoisting
        }

        // ---- 8 col-blocks: 16 x {1 ds_read_b128 + 2 MFMA}; acc pair only
#pragma unroll 1
        for (int n = 0; n < 8; ++n) {
            f32x16 aA, aB;
#pragma unroll
            for (int e = 0; e < 16; ++e) { aA[e] = b2v[n]; aB[e] = b2v[n]; }
            const short8* __restrict__ bl = Blds + n * 1024 + lane;
            __builtin_amdgcn_s_setprio(1);
#pragma unroll
            for (int kk = 0; kk < 16; ++kk) {
                short8 bf = bl[kk * 64];
                aA = __builtin_amdgcn_mfma_f32_32x32x16_bf16(A0[kk], bf, aA, 0, 0, 0);
                aB = __builtin_amdgcn_mfma_f32_32x32x16_bf16(A1[kk], bf, aB, 0, 0, 0);
            }
            __builtin_amdgcn_s_setprio(0);
            float s = 0.f;
#pragma unroll
            for (int e = 0; e < 16; ++e)
                s += fmaxf(aA[e], 0.f) + fmaxf(aB[e], 0.f);
            jobsum[n] += s;
        }
    }

    // ---- write: combine h halves, one store per (wave, n)
#pragma unroll
    for (int n = 0; n < 8; ++n) {
        jobsum[n] += __shfl_xor(jobsum[n], 32);
        if (h == 0)
            partials[((size_t)(b * 256 + n * 32 + l31)) * 1024 + r * 8 + w] = jobsum[n];
    }
}

// ---- final: reduce [b][col][1024 slots] + tail MLP, 512 thr
__global__ __launch_bounds__(512) void finalK(const float* __restrict__ partials,
                                              const float* __restrict__ w3,
                                              const float* __restrict__ b3,
                                              const float* __restrict__ w4,
                                              const float* __restrict__ b4,
                                              const float* __restrict__ w5,
                                              const float* __restrict__ b5,
                                              float* __restrict__ out) {
    __shared__ float su[2][256], mid[2][256], o[2][256];
    int tid = threadIdx.x;
    int b = tid >> 8, c = tid & 255;
    const float4v* pv = reinterpret_cast<const float4v*>(
        partials + ((size_t)(b * 256 + c)) * 1024);
    float s = 0.f;
#pragma unroll 8
    for (int q = 0; q < 256; ++q) {
        float4v v = pv[q];
        s += v[0] + v[1] + v[2] + v[3];
    }
    su[b][c] = s;
    __syncthreads();
    float m = 262144.0f * b3[c];
    for (int k = 0; k < 256; ++k) m += su[b][k] * w3[k * 256 + c];
    mid[b][c] = m;
    __syncthreads();
    float ov = b4[c];
    for (int k = 0; k < 256; ++k) ov += mid[b][k] * w4[k * 256 + c];
    o[b][c] = fmaxf(ov, 0.f);
    __syncthreads();
    if (c < 64) {
        float rr = b5[c];
        for (int k = 0; k < 256; ++k) rr += o[b][k] * w5[k * 64 + c];
        out[b * 64 + c] = rr;
    }
}

extern "C" void kernel_launch(void* const* d_in, const int* in_sizes, int n_in,
                              void* d_out, int out_size, void* d_ws, size_t ws_size,
                              hipStream_t stream) {
    const float* in = (const float*)d_in[0];
    const float* w1 = (const float*)d_in[1];
    const float* b1 = (const float*)d_in[2];
    const float* w2 = (const float*)d_in[3];
    const float* b2 = (const float*)d_in[4];
    const float* w3 = (const float*)d_in[5];
    const float* b3 = (const float*)d_in[6];
    const float* w4 = (const float*)d_in[7];
    const float* b4 = (const float*)d_in[8];
    const float* w5 = (const float*)d_in[9];
    const float* b5 = (const float*)d_in[10];
    float* out = (float*)d_out;

    char* ws = (char*)d_ws;
    float* hi       = (float*)(ws);                                   // 1 MB
    float* hcb      = (float*)(ws + (1u << 20));                      // 1 MB
    short* bfrag    = (short*)(ws + (2u << 20));                      // 128 KB
    float* partials = (float*)(ws + (2u << 20) + (1u << 18));         // 2 MB (2x256x1024)

    prep<<<512, 256, 0, stream>>>(in, w1, b1, w2, hi, hcb, bfrag);
    big<<<256, 512, 0, stream>>>(hi, hcb, (const short8*)bfrag, b2, partials);
    finalK<<<1, 512, 0, stream>>>(partials, w3, b3, w4, b4, w5, b5, out);
}

// Round 13
// 89.734 us; speedup vs baseline: 1.7305x; 1.7305x over previous
//
#include <hip/hip_runtime.h>

// B=2, D=64, N=512, H=256, OUT=64
// mid[b] = sum_{c,i} relu( relu(hi[b,i,:]+hcb[b,c,:]) @ w2 + b2 ) @ w3 + N^2*b3
// out = relu(mid @ w4 + b4) @ w5 + b5
//
// big v13: barrier-free main loop (v12) +
//  - hc rows staged in LDS (block-shared, 8KB, pad-260 conflict-free):
//    gen global loads 96 -> 32 per job
//  - 4 independent MFMA accumulator chains (2 n-blocks/iter, acc=64 regs)
//  - parallel reduceK (512 blocks) instead of serial in-finalK reduce

using f32x16  = __attribute__((ext_vector_type(16))) float;
using short8  = __attribute__((ext_vector_type(8))) short;
using float4v = __attribute__((ext_vector_type(4))) float;

__device__ __forceinline__ short f2bf(float f) {
    unsigned u = __float_as_uint(f);
    unsigned r = u + 0x7FFFu + ((u >> 16) & 1u);   // RNE
    return (short)(r >> 16);
}

__device__ __forceinline__ short8 relu_pack8(float4v lo, float4v hi4) {
#pragma unroll
    for (int e = 0; e < 4; ++e) {
        lo[e]  = fmaxf(lo[e], 0.f);
        hi4[e] = fmaxf(hi4[e], 0.f);
    }
    union { short8 s; unsigned u[4]; } r;
    asm("v_cvt_pk_bf16_f32 %0, %1, %2" : "=v"(r.u[0]) : "v"(lo[0]),  "v"(lo[1]));
    asm("v_cvt_pk_bf16_f32 %0, %1, %2" : "=v"(r.u[1]) : "v"(lo[2]),  "v"(lo[3]));
    asm("v_cvt_pk_bf16_f32 %0, %1, %2" : "=v"(r.u[2]) : "v"(hi4[0]), "v"(hi4[1]));
    asm("v_cvt_pk_bf16_f32 %0, %1, %2" : "=v"(r.u[3]) : "v"(hi4[2]), "v"(hi4[3]));
    return r.s;
}

// ---- prep: blocks [0,256): hi/hcb (4 n-cols per block); [256,512): frag-ordered w2
__global__ __launch_bounds__(256) void prep(const float* __restrict__ in,
                                            const float* __restrict__ w1,
                                            const float* __restrict__ b1,
                                            const float* __restrict__ w2,
                                            float* __restrict__ hi,
                                            float* __restrict__ hcb,
                                            short* __restrict__ bfrag) {
    int tid = threadIdx.x;
    int bidx = blockIdx.x;
    if (bidx < 256) {
        int b = bidx >> 7, n0 = (bidx & 127) * 4;
        __shared__ float xs[4][64];
        {
            int nn = tid >> 6, d = tid & 63;
            xs[nn][d] = in[(size_t)(b * 64 + d) * 512 + n0 + nn];
        }
        __syncthreads();
        float a0[4] = {0.f, 0.f, 0.f, 0.f}, a1[4] = {0.f, 0.f, 0.f, 0.f};
#pragma unroll 8
        for (int d = 0; d < 64; ++d) {
            float wA = w1[d * 256 + tid];
            float wB = w1[(64 + d) * 256 + tid];
#pragma unroll
            for (int nn = 0; nn < 4; ++nn) {
                a0[nn] += xs[nn][d] * wA;
                a1[nn] += xs[nn][d] * wB;
            }
        }
        float bb = b1[tid];
#pragma unroll
        for (int nn = 0; nn < 4; ++nn) {
            size_t o = (size_t)(b * 512 + n0 + nn) * 256 + tid;
            hi[o]  = a0[nn];
            hcb[o] = a1[nn] + bb;
        }
    } else {
        // off = ((n*16+kk)*64 + h*32+col)*8 + j ; value bf16(w2[k][ncol])
        int idx = (bidx - 256) * 256 + tid;        // [0, 65536)
        int k = idx >> 8, ncol = idx & 255;
        int n = ncol >> 5, col = ncol & 31;
        int kk = k >> 4, h = (k >> 3) & 1, j = k & 7;
        int off = (((n * 16 + kk) * 64) + h * 32 + col) * 8 + j;
        bfrag[off] = f2bf(w2[k * 256 + ncol]);
    }
}

// ---- big v13: 256 blocks x 512 threads, 136 KB LDS
__global__ __launch_bounds__(512, 1) void big(const float* __restrict__ hi_,
                                              const float* __restrict__ hcb_,
                                              const short8* __restrict__ bfrag,
                                              const float* __restrict__ b2,
                                              float* __restrict__ partials) {
    __shared__ __align__(16) short8 Blds[8192];      // 128 KB: [n 8][kk 16][lane 64]
    __shared__ __align__(16) float hcLds[8 * 260];   // 8.3 KB, pad-260

    const int tid = threadIdx.x;                  // 0..511
    const int bid = blockIdx.x;                   // [0,256)
    const int b = bid >> 7, r = bid & 127;
    const int C = r >> 1;                         // block c-octet [0,64)

    // stage whole B (linear) + hc rows C*8..C*8+7 (f32)
#pragma unroll
    for (int q = 0; q < 16; ++q) Blds[q * 512 + tid] = bfrag[q * 512 + tid];
    {
        int row = tid >> 6, j4 = (tid & 63) * 4;
        float4v v = *reinterpret_cast<const float4v*>(
            hcb_ + (size_t)b * 131072 + (size_t)(C * 8 + row) * 256 + j4);
        *reinterpret_cast<float4v*>(&hcLds[row * 260 + j4]) = v;
    }
    __syncthreads();                              // the ONLY block-wide barrier

    const int w = tid >> 6, lane = tid & 63;
    const int l31 = lane & 31, h = lane >> 5;
    const int ip = l31 & 7, cq4 = l31 >> 3;

    const int Ibase = (r & 1) * 32 + w * 4;       // i-octet base

    const float* __restrict__ hib = hi_ + (size_t)b * 131072;
    const float* __restrict__ hcl0 = &hcLds[cq4 * 260 + h * 8];
    const float* __restrict__ hcl1 = &hcLds[(cq4 + 4) * 260 + h * 8];

    float b2v[8];
#pragma unroll
    for (int n = 0; n < 8; ++n) b2v[n] = b2[n * 32 + l31];
    float jobsum[8] = {0.f, 0.f, 0.f, 0.f, 0.f, 0.f, 0.f, 0.f};

#pragma unroll 1
    for (int t = 0; t < 4; ++t) {
        const int I = Ibase + t;
        const float* __restrict__ hirow = hib + (size_t)(I * 8 + ip) * 256 + h * 8;

        // ---- gen: two 32-row A tiles into 128 fragment regs (hi global, hc LDS)
        short8 A0[16], A1[16];
#pragma unroll
        for (int kk = 0; kk < 16; ++kk) {
            float4v x0  = *reinterpret_cast<const float4v*>(hirow + kk * 16);
            float4v x1  = *reinterpret_cast<const float4v*>(hirow + kk * 16 + 4);
            float4v c00 = *reinterpret_cast<const float4v*>(hcl0 + kk * 16);
            float4v c01 = *reinterpret_cast<const float4v*>(hcl0 + kk * 16 + 4);
            float4v c10 = *reinterpret_cast<const float4v*>(hcl1 + kk * 16);
            float4v c11 = *reinterpret_cast<const float4v*>(hcl1 + kk * 16 + 4);
            A0[kk] = relu_pack8(x0 + c00, x1 + c01);
            A1[kk] = relu_pack8(x0 + c10, x1 + c11);
            if (kk & 1) __builtin_amdgcn_sched_barrier(0);   // cap hoisting
        }

        // ---- 4 iters x 2 n-blocks: 4 independent MFMA chains (acc = 64 regs)
#pragma unroll 1
        for (int np = 0; np < 4; ++np) {
            f32x16 aA0, aB0, aA1, aB1;
#pragma unroll
            for (int e = 0; e < 16; ++e) {
                aA0[e] = b2v[np];     aB0[e] = b2v[np];
                aA1[e] = b2v[np + 4]; aB1[e] = b2v[np + 4];
            }
            const short8* __restrict__ bl0 = Blds + np * 1024 + lane;
            const short8* __restrict__ bl1 = Blds + (np + 4) * 1024 + lane;
            __builtin_amdgcn_s_setprio(1);
#pragma unroll
            for (int kk = 0; kk < 16; ++kk) {
                short8 bf0 = bl0[kk * 64];
                short8 bf1 = bl1[kk * 64];
                aA0 = __builtin_amdgcn_mfma_f32_32x32x16_bf16(A0[kk], bf0, aA0, 0, 0, 0);
                aB0 = __builtin_amdgcn_mfma_f32_32x32x16_bf16(A1[kk], bf0, aB0, 0, 0, 0);
                aA1 = __builtin_amdgcn_mfma_f32_32x32x16_bf16(A0[kk], bf1, aA1, 0, 0, 0);
                aB1 = __builtin_amdgcn_mfma_f32_32x32x16_bf16(A1[kk], bf1, aB1, 0, 0, 0);
            }
            __builtin_amdgcn_s_setprio(0);
            float s0 = 0.f, s1 = 0.f;
#pragma unroll
            for (int e = 0; e < 16; ++e) {
                s0 += fmaxf(aA0[e], 0.f) + fmaxf(aB0[e], 0.f);
                s1 += fmaxf(aA1[e], 0.f) + fmaxf(aB1[e], 0.f);
            }
            jobsum[np]     += s0;
            jobsum[np + 4] += s1;
        }
    }

    // ---- write: combine h halves, one store per (wave, n)
#pragma unroll
    for (int n = 0; n < 8; ++n) {
        jobsum[n] += __shfl_xor(jobsum[n], 32);
        if (h == 0)
            partials[((size_t)(b * 256 + n * 32 + l31)) * 1024 + r * 8 + w] = jobsum[n];
    }
}

// ---- reduceK: 512 blocks (one per (b,col)), 256 thr; sums 1024 slots
__global__ __launch_bounds__(256) void reduceK(const float* __restrict__ partials,
                                               float* __restrict__ su_g) {
    int tid = threadIdx.x, blk = blockIdx.x;      // blk = b*256 + col
    const float4v* pv = reinterpret_cast<const float4v*>(partials + (size_t)blk * 1024);
    float4v v = pv[tid];
    float s = v[0] + v[1] + v[2] + v[3];
#pragma unroll
    for (int d = 1; d < 64; d <<= 1) s += __shfl_xor(s, d);
    __shared__ float wsum[4];
    if ((tid & 63) == 0) wsum[tid >> 6] = s;
    __syncthreads();
    if (tid == 0) su_g[blk] = wsum[0] + wsum[1] + wsum[2] + wsum[3];
}

// ---- final tail MLP (reads 512-float su_g), 512 thr
__global__ __launch_bounds__(512) void finalK(const float* __restrict__ su_g,
                                              const float* __restrict__ w3,
                                              const float* __restrict__ b3,
                                              const float* __restrict__ w4,
                                              const float* __restrict__ b4,
                                              const float* __restrict__ w5,
                                              const float* __restrict__ b5,
                                              float* __restrict__ out) {
    __shared__ float su[2][256], mid[2][256], o[2][256];
    int tid = threadIdx.x;
    int b = tid >> 8, c = tid & 255;
    su[b][c] = su_g[b * 256 + c];
    __syncthreads();
    float m = 262144.0f * b3[c];
    for (int k = 0; k < 256; ++k) m += su[b][k] * w3[k * 256 + c];
    mid[b][c] = m;
    __syncthreads();
    float ov = b4[c];
    for (int k = 0; k < 256; ++k) ov += mid[b][k] * w4[k * 256 + c];
    o[b][c] = fmaxf(ov, 0.f);
    __syncthreads();
    if (c < 64) {
        float rr = b5[c];
        for (int k = 0; k < 256; ++k) rr += o[b][k] * w5[k * 64 + c];
        out[b * 64 + c] = rr;
    }
}

extern "C" void kernel_launch(void* const* d_in, const int* in_sizes, int n_in,
                              void* d_out, int out_size, void* d_ws, size_t ws_size,
                              hipStream_t stream) {
    const float* in = (const float*)d_in[0];
    const float* w1 = (const float*)d_in[1];
    const float* b1 = (const float*)d_in[2];
    const float* w2 = (const float*)d_in[3];
    const float* b2 = (const float*)d_in[4];
    const float* w3 = (const float*)d_in[5];
    const float* b3 = (const float*)d_in[6];
    const float* w4 = (const float*)d_in[7];
    const float* b4 = (const float*)d_in[8];
    const float* w5 = (const float*)d_in[9];
    const float* b5 = (const float*)d_in[10];
    float* out = (float*)d_out;

    char* ws = (char*)d_ws;
    float* hi       = (float*)(ws);                                   // 1 MB
    float* hcb      = (float*)(ws + (1u << 20));                      // 1 MB
    short* bfrag    = (short*)(ws + (2u << 20));                      // 128 KB
    float* partials = (float*)(ws + (2u << 20) + (1u << 18));         // 2 MB (2x256x1024)
    float* su_g     = (float*)(ws + (4u << 20) + (1u << 18));         // 2 KB

    prep<<<512, 256, 0, stream>>>(in, w1, b1, w2, hi, hcb, bfrag);
    big<<<256, 512, 0, stream>>>(hi, hcb, (const short8*)bfrag, b2, partials);
    reduceK<<<512, 256, 0, stream>>>(partials, su_g);
    finalK<<<1, 512, 0, stream>>>(su_g, w3, b3, w4, b4, w5, b5, out);
}

// Round 14
// 89.423 us; speedup vs baseline: 1.7365x; 1.0035x over previous
//
#include <hip/hip_runtime.h>

// B=2, D=64, N=512, H=256, OUT=64
// mid[b] = sum_{c,i} relu( relu(hi[b,i,:]+hcb[b,c,:]) @ w2 + b2 ) @ w3 + N^2*b3
// out = relu(mid @ w4 + b4) @ w5 + b5
//
// big v14 = v13 + anti-phase stagger (waves 4-7 s_sleep ~5k cy after staging,
// so the two waves on each SIMD alternate gen-VALU vs MFMA phases) +
// dechained epilogue (4 independent accumulators) + looser gen sched window.

using f32x16  = __attribute__((ext_vector_type(16))) float;
using short8  = __attribute__((ext_vector_type(8))) short;
using float4v = __attribute__((ext_vector_type(4))) float;

__device__ __forceinline__ short f2bf(float f) {
    unsigned u = __float_as_uint(f);
    unsigned r = u + 0x7FFFu + ((u >> 16) & 1u);   // RNE
    return (short)(r >> 16);
}

__device__ __forceinline__ short8 relu_pack8(float4v lo, float4v hi4) {
#pragma unroll
    for (int e = 0; e < 4; ++e) {
        lo[e]  = fmaxf(lo[e], 0.f);
        hi4[e] = fmaxf(hi4[e], 0.f);
    }
    union { short8 s; unsigned u[4]; } r;
    asm("v_cvt_pk_bf16_f32 %0, %1, %2" : "=v"(r.u[0]) : "v"(lo[0]),  "v"(lo[1]));
    asm("v_cvt_pk_bf16_f32 %0, %1, %2" : "=v"(r.u[1]) : "v"(lo[2]),  "v"(lo[3]));
    asm("v_cvt_pk_bf16_f32 %0, %1, %2" : "=v"(r.u[2]) : "v"(hi4[0]), "v"(hi4[1]));
    asm("v_cvt_pk_bf16_f32 %0, %1, %2" : "=v"(r.u[3]) : "v"(hi4[2]), "v"(hi4[3]));
    return r.s;
}

// ---- prep: blocks [0,256): hi/hcb (4 n-cols per block); [256,512): frag-ordered w2
__global__ __launch_bounds__(256) void prep(const float* __restrict__ in,
                                            const float* __restrict__ w1,
                                            const float* __restrict__ b1,
                                            const float* __restrict__ w2,
                                            float* __restrict__ hi,
                                            float* __restrict__ hcb,
                                            short* __restrict__ bfrag) {
    int tid = threadIdx.x;
    int bidx = blockIdx.x;
    if (bidx < 256) {
        int b = bidx >> 7, n0 = (bidx & 127) * 4;
        __shared__ float xs[4][64];
        {
            int nn = tid >> 6, d = tid & 63;
            xs[nn][d] = in[(size_t)(b * 64 + d) * 512 + n0 + nn];
        }
        __syncthreads();
        float a0[4] = {0.f, 0.f, 0.f, 0.f}, a1[4] = {0.f, 0.f, 0.f, 0.f};
#pragma unroll 8
        for (int d = 0; d < 64; ++d) {
            float wA = w1[d * 256 + tid];
            float wB = w1[(64 + d) * 256 + tid];
#pragma unroll
            for (int nn = 0; nn < 4; ++nn) {
                a0[nn] += xs[nn][d] * wA;
                a1[nn] += xs[nn][d] * wB;
            }
        }
        float bb = b1[tid];
#pragma unroll
        for (int nn = 0; nn < 4; ++nn) {
            size_t o = (size_t)(b * 512 + n0 + nn) * 256 + tid;
            hi[o]  = a0[nn];
            hcb[o] = a1[nn] + bb;
        }
    } else {
        // off = ((n*16+kk)*64 + h*32+col)*8 + j ; value bf16(w2[k][ncol])
        int idx = (bidx - 256) * 256 + tid;        // [0, 65536)
        int k = idx >> 8, ncol = idx & 255;
        int n = ncol >> 5, col = ncol & 31;
        int kk = k >> 4, h = (k >> 3) & 1, j = k & 7;
        int off = (((n * 16 + kk) * 64) + h * 32 + col) * 8 + j;
        bfrag[off] = f2bf(w2[k * 256 + ncol]);
    }
}

// ---- big v14: 256 blocks x 512 threads, 136 KB LDS
__global__ __launch_bounds__(512, 1) void big(const float* __restrict__ hi_,
                                              const float* __restrict__ hcb_,
                                              const short8* __restrict__ bfrag,
                                              const float* __restrict__ b2,
                                              float* __restrict__ partials) {
    __shared__ __align__(16) short8 Blds[8192];      // 128 KB: [n 8][kk 16][lane 64]
    __shared__ __align__(16) float hcLds[8 * 260];   // 8.3 KB, pad-260

    const int tid = threadIdx.x;                  // 0..511
    const int bid = blockIdx.x;                   // [0,256)
    const int b = bid >> 7, r = bid & 127;
    const int C = r >> 1;                         // block c-octet [0,64)

    // stage whole B (linear) + hc rows C*8..C*8+7 (f32)
#pragma unroll
    for (int q = 0; q < 16; ++q) Blds[q * 512 + tid] = bfrag[q * 512 + tid];
    {
        int row = tid >> 6, j4 = (tid & 63) * 4;
        float4v v = *reinterpret_cast<const float4v*>(
            hcb_ + (size_t)b * 131072 + (size_t)(C * 8 + row) * 256 + j4);
        *reinterpret_cast<float4v*>(&hcLds[row * 260 + j4]) = v;
    }
    __syncthreads();                              // the ONLY block-wide barrier

    const int w = tid >> 6, lane = tid & 63;

    // ---- anti-phase stagger: waves 4-7 (SIMD partners of 0-3) sleep ~5k cy
    if (w >= 4) {
#pragma unroll
        for (int z = 0; z < 10; ++z) __builtin_amdgcn_s_sleep(8);
    }

    const int l31 = lane & 31, h = lane >> 5;
    const int ip = l31 & 7, cq4 = l31 >> 3;

    const int Ibase = (r & 1) * 32 + w * 4;       // i-octet base

    const float* __restrict__ hib = hi_ + (size_t)b * 131072;
    const float* __restrict__ hcl0 = &hcLds[cq4 * 260 + h * 8];
    const float* __restrict__ hcl1 = &hcLds[(cq4 + 4) * 260 + h * 8];

    float b2v[8];
#pragma unroll
    for (int n = 0; n < 8; ++n) b2v[n] = b2[n * 32 + l31];
    float jobsum[8] = {0.f, 0.f, 0.f, 0.f, 0.f, 0.f, 0.f, 0.f};

#pragma unroll 1
    for (int t = 0; t < 4; ++t) {
        const int I = Ibase + t;
        const float* __restrict__ hirow = hib + (size_t)(I * 8 + ip) * 256 + h * 8;

        // ---- gen: two 32-row A tiles into 128 fragment regs (hi global, hc LDS)
        short8 A0[16], A1[16];
#pragma unroll
        for (int kk = 0; kk < 16; ++kk) {
            float4v x0  = *reinterpret_cast<const float4v*>(hirow + kk * 16);
            float4v x1  = *reinterpret_cast<const float4v*>(hirow + kk * 16 + 4);
            float4v c00 = *reinterpret_cast<const float4v*>(hcl0 + kk * 16);
            float4v c01 = *reinterpret_cast<const float4v*>(hcl0 + kk * 16 + 4);
            float4v c10 = *reinterpret_cast<const float4v*>(hcl1 + kk * 16);
            float4v c11 = *reinterpret_cast<const float4v*>(hcl1 + kk * 16 + 4);
            A0[kk] = relu_pack8(x0 + c00, x1 + c01);
            A1[kk] = relu_pack8(x0 + c10, x1 + c11);
            if ((kk & 3) == 3) __builtin_amdgcn_sched_barrier(0);   // cap hoisting
        }

        // ---- 4 iters x 2 n-blocks: 4 independent MFMA chains (acc = 64 regs)
#pragma unroll 1
        for (int np = 0; np < 4; ++np) {
            f32x16 aA0, aB0, aA1, aB1;
#pragma unroll
            for (int e = 0; e < 16; ++e) {
                aA0[e] = b2v[np];     aB0[e] = b2v[np];
                aA1[e] = b2v[np + 4]; aB1[e] = b2v[np + 4];
            }
            const short8* __restrict__ bl0 = Blds + np * 1024 + lane;
            const short8* __restrict__ bl1 = Blds + (np + 4) * 1024 + lane;
            __builtin_amdgcn_s_setprio(1);
#pragma unroll
            for (int kk = 0; kk < 16; ++kk) {
                short8 bf0 = bl0[kk * 64];
                short8 bf1 = bl1[kk * 64];
                aA0 = __builtin_amdgcn_mfma_f32_32x32x16_bf16(A0[kk], bf0, aA0, 0, 0, 0);
                aB0 = __builtin_amdgcn_mfma_f32_32x32x16_bf16(A1[kk], bf0, aB0, 0, 0, 0);
                aA1 = __builtin_amdgcn_mfma_f32_32x32x16_bf16(A0[kk], bf1, aA1, 0, 0, 0);
                aB1 = __builtin_amdgcn_mfma_f32_32x32x16_bf16(A1[kk], bf1, aB1, 0, 0, 0);
            }
            __builtin_amdgcn_s_setprio(0);
            // dechained epilogue: 4 independent accumulator chains
            float s0a = 0.f, s0b = 0.f, s1a = 0.f, s1b = 0.f;
#pragma unroll
            for (int e = 0; e < 16; e += 2) {
                s0a += fmaxf(aA0[e], 0.f)     + fmaxf(aB0[e], 0.f);
                s0b += fmaxf(aA0[e + 1], 0.f) + fmaxf(aB0[e + 1], 0.f);
                s1a += fmaxf(aA1[e], 0.f)     + fmaxf(aB1[e], 0.f);
                s1b += fmaxf(aA1[e + 1], 0.f) + fmaxf(aB1[e + 1], 0.f);
            }
            jobsum[np]     += s0a + s0b;
            jobsum[np + 4] += s1a + s1b;
        }
    }

    // ---- write: combine h halves, one store per (wave, n)
#pragma unroll
    for (int n = 0; n < 8; ++n) {
        jobsum[n] += __shfl_xor(jobsum[n], 32);
        if (h == 0)
            partials[((size_t)(b * 256 + n * 32 + l31)) * 1024 + r * 8 + w] = jobsum[n];
    }
}

// ---- reduceK: 512 blocks (one per (b,col)), 256 thr; sums 1024 slots
__global__ __launch_bounds__(256) void reduceK(const float* __restrict__ partials,
                                               float* __restrict__ su_g) {
    int tid = threadIdx.x, blk = blockIdx.x;      // blk = b*256 + col
    const float4v* pv = reinterpret_cast<const float4v*>(partials + (size_t)blk * 1024);
    float4v v = pv[tid];
    float s = v[0] + v[1] + v[2] + v[3];
#pragma unroll
    for (int d = 1; d < 64; d <<= 1) s += __shfl_xor(s, d);
    __shared__ float wsum[4];
    if ((tid & 63) == 0) wsum[tid >> 6] = s;
    __syncthreads();
    if (tid == 0) su_g[blk] = wsum[0] + wsum[1] + wsum[2] + wsum[3];
}

// ---- final tail MLP (reads 512-float su_g), 512 thr
__global__ __launch_bounds__(512) void finalK(const float* __restrict__ su_g,
                                              const float* __restrict__ w3,
                                              const float* __restrict__ b3,
                                              const float* __restrict__ w4,
                                              const float* __restrict__ b4,
                                              const float* __restrict__ w5,
                                              const float* __restrict__ b5,
                                              float* __restrict__ out) {
    __shared__ float su[2][256], mid[2][256], o[2][256];
    int tid = threadIdx.x;
    int b = tid >> 8, c = tid & 255;
    su[b][c] = su_g[b * 256 + c];
    __syncthreads();
    float m = 262144.0f * b3[c];
    for (int k = 0; k < 256; ++k) m += su[b][k] * w3[k * 256 + c];
    mid[b][c] = m;
    __syncthreads();
    float ov = b4[c];
    for (int k = 0; k < 256; ++k) ov += mid[b][k] * w4[k * 256 + c];
    o[b][c] = fmaxf(ov, 0.f);
    __syncthreads();
    if (c < 64) {
        float rr = b5[c];
        for (int k = 0; k < 256; ++k) rr += o[b][k] * w5[k * 64 + c];
        out[b * 64 + c] = rr;
    }
}

extern "C" void kernel_launch(void* const* d_in, const int* in_sizes, int n_in,
                              void* d_out, int out_size, void* d_ws, size_t ws_size,
                              hipStream_t stream) {
    const float* in = (const float*)d_in[0];
    const float* w1 = (const float*)d_in[1];
    const float* b1 = (const float*)d_in[2];
    const float* w2 = (const float*)d_in[3];
    const float* b2 = (const float*)d_in[4];
    const float* w3 = (const float*)d_in[5];
    const float* b3 = (const float*)d_in[6];
    const float* w4 = (const float*)d_in[7];
    const float* b4 = (const float*)d_in[8];
    const float* w5 = (const float*)d_in[9];
    const float* b5 = (const float*)d_in[10];
    float* out = (float*)d_out;

    char* ws = (char*)d_ws;
    float* hi       = (float*)(ws);                                   // 1 MB
    float* hcb      = (float*)(ws + (1u << 20));                      // 1 MB
    short* bfrag    = (short*)(ws + (2u << 20));                      // 128 KB
    float* partials = (float*)(ws + (2u << 20) + (1u << 18));         // 2 MB (2x256x1024)
    float* su_g     = (float*)(ws + (4u << 20) + (1u << 18));         // 2 KB

    prep<<<512, 256, 0, stream>>>(in, w1, b1, w2, hi, hcb, bfrag);
    big<<<256, 512, 0, stream>>>(hi, hcb, (const short8*)bfrag, b2, partials);
    reduceK<<<512, 256, 0, stream>>>(partials, su_g);
    finalK<<<1, 512, 0, stream>>>(su_g, w3, b3, w4, b4, w5, b5, out);
}